// Round 8
// baseline (115.703 us; speedup 1.0000x reference)
//
#include <hip/hip_runtime.h>

// MRConv1d: B=4, N=10000, C=128, K=16, OUT=128
// out[b,n,o] = relu( sum_c2 feat[b,n,c2]*W[o,c2] + bias[o] )
// feat[b,n,2c]   = x[b,n,c]
// feat[b,n,2c+1] = max_k( x[b, e0[b,n,k], c] - x[b, e1[b,n,k], c] )
//
// R8: wave-autonomous blocks (64 threads = 1 wave, 8 nodes each): gather,
// cross-quarter shfl max, MFMA, store -- no inter-wave barrier, so the
// per-CU outstanding-request queue (the R3..R7 plateau's wall) never drains
// at a block-internal sync. Feature k-order is [x(0..127) | rel(0..127)];
// the reference's channel interleave is folded into the Wh packing.

#define Bn 4
#define Nn 10000
#define Cn 128
#define Kn 16
#define OUTn 128
#define Mw 8            // nodes per wave/block
#define NTn 1250        // node tiles (10000/8)
#define FPAD 8          // sfeat row pad (row = 264 halfs = 528 B)

typedef _Float16 half8v __attribute__((ext_vector_type(8)));
typedef float floatx4 __attribute__((ext_vector_type(4)));

// ---- fused prep: blocks [0,2500) convert x fp32->f16; blocks [2500,2516)
// pack W into f16 B-fragments for mfma_f32_16x16x32_f16 with the k-dim
// permutation matching sfeat's [x | rel] layout:
//   our k index idx -> original c2 = idx<128 ? 2*idx : 2*idx-255.
// Wh[((tile*8 + step)*64 + lane)*8 + j] = (f16)W[o][c2(idx)]
//   with o = tile*16 + (lane&15), idx = step*32 + (lane>>4)*8 + j.
__global__ __launch_bounds__(256) void prep(const float* __restrict__ x,
                                            const float* __restrict__ W,
                                            _Float16* __restrict__ xh,
                                            _Float16* __restrict__ Wh) {
    if (blockIdx.x < 2500) {
        int i = blockIdx.x * 256 + threadIdx.x;      // 0..639999, 8 floats each
        const floatx4* x4 = (const floatx4*)x;
        floatx4 a = x4[2 * i];
        floatx4 c = x4[2 * i + 1];
        union { _Float16 h[8]; uint4 q; } pk;
        pk.h[0] = (_Float16)a.x; pk.h[1] = (_Float16)a.y;
        pk.h[2] = (_Float16)a.z; pk.h[3] = (_Float16)a.w;
        pk.h[4] = (_Float16)c.x; pk.h[5] = (_Float16)c.y;
        pk.h[6] = (_Float16)c.z; pk.h[7] = (_Float16)c.w;
        *(uint4*)(xh + 8 * (size_t)i) = pk.q;
    } else {
        int tid = (blockIdx.x - 2500) * 256 + threadIdx.x;   // 0..4095
        int lane = tid & 63;
        int step = (tid >> 6) & 7;
        int tile = tid >> 9;
        int o = tile * 16 + (lane & 15);
        int quad = lane >> 4;
        union { _Float16 h[8]; uint4 q; } pk;
#pragma unroll
        for (int j = 0; j < 8; ++j) {
            int idx = step * 32 + quad * 8 + j;
            int c2 = (idx < 128) ? (2 * idx) : (2 * idx - 255);
            pk.h[j] = (_Float16)W[o * (2 * Cn) + c2];
        }
        *(uint4*)(Wh + (size_t)tid * 8) = pk.q;
    }
}

__global__ __launch_bounds__(64, 4) void mrconv_kernel(
    const _Float16* __restrict__ xh, const int* __restrict__ edge,
    const _Float16* __restrict__ Wh, const float* __restrict__ bias,
    float* __restrict__ out)
{
    __shared__ int sidx[2][Mw][Kn];                 // 1 KB
    // 16 rows declared (MFMA A-frag reads rows 0..15); rows 8..15 are unused
    // garbage -- finite or NaN, it only reaches acc rows >= 8, never stored.
    __shared__ _Float16 sfeat[16][2 * Cn + FPAD];   // [x(128) | rel(128)] per row

    // XCD-aware mapping: batch b pinned to XCD slots {b, b+4}; each XCD's L2
    // serves one 2.56 MB f16 batch slice (fits 4 MiB). grid 5000 = 625*8.
    int bi = blockIdx.x;
    int slot = bi & 7;
    int b = slot & 3;
    int nb = (bi >> 3) * 2 + (slot >> 2);
    if (nb >= NTn) return;
    const int n0 = nb * Mw;
    const int gbase = b * Nn + n0;

    const int lane = threadIdx.x;     // 0..63 (one wave)
    const int q = lane >> 4;          // quarter 0..3
    const int l16 = lane & 15;
    const int ch = l16 * 8;           // 8 channels per lane

    // stage edge indices: 2*8*16 = 256 ints, 4 per lane
#pragma unroll
    for (int u = 0; u < 4; ++u) {
        int i = u * 64 + lane;
        int s = i >> 7;
        int m = (i >> 4) & 7;
        int k = i & 15;
        sidx[s][m][k] = edge[s * (Bn * Nn * Kn) + (gbase + m) * Kn + k];
    }
    __syncthreads();   // single-wave block: near-free

    const _Float16* xbb = xh + (size_t)b * Nn * Cn;

    // self rows: 2 instrs, instr s covers nodes 4s+q; write to sfeat x-half
#pragma unroll
    for (int s = 0; s < 2; ++s) {
        half8v sv = *(const half8v*)(xbb + (n0 + 4 * s + q) * Cn + ch);
        union { half8v h; uint4 u; } pk; pk.h = sv;
        *(uint4*)&sfeat[4 * s + q][ch] = pk.u;
    }

    // gather + max-relative: per node, quarter q owns k in [4q, 4q+4);
    // each VMEM instr covers 4 rows (one per quarter) x 16 lanes x 16 B.
#pragma unroll
    for (int m = 0; m < Mw; ++m) {
        const int4 ja = *(const int4*)&sidx[0][m][4 * q];   // broadcast b128
        const int4 ia = *(const int4*)&sidx[1][m][4 * q];
        half8v vj[4], vi[4];
        vj[0] = *(const half8v*)(xbb + ja.x * Cn + ch);
        vj[1] = *(const half8v*)(xbb + ja.y * Cn + ch);
        vj[2] = *(const half8v*)(xbb + ja.z * Cn + ch);
        vj[3] = *(const half8v*)(xbb + ja.w * Cn + ch);
        vi[0] = *(const half8v*)(xbb + ia.x * Cn + ch);
        vi[1] = *(const half8v*)(xbb + ia.y * Cn + ch);
        vi[2] = *(const half8v*)(xbb + ia.z * Cn + ch);
        vi[3] = *(const half8v*)(xbb + ia.w * Cn + ch);
        half8v r = vj[0] - vi[0];
#pragma unroll
        for (int g = 1; g < 4; ++g)
            r = __builtin_elementwise_max(r, vj[g] - vi[g]);
        // cross-quarter max: lanes q and q^1 (xor 16), then q^2 (xor 32)
        union { half8v h; int i4[4]; } ru, rs;
        ru.h = r;
#pragma unroll
        for (int e = 0; e < 4; ++e) rs.i4[e] = __shfl_xor(ru.i4[e], 16, 64);
        ru.h = __builtin_elementwise_max(ru.h, rs.h);
#pragma unroll
        for (int e = 0; e < 4; ++e) rs.i4[e] = __shfl_xor(ru.i4[e], 32, 64);
        ru.h = __builtin_elementwise_max(ru.h, rs.h);
        if (lane < 16) {
            union { half8v h; uint4 u; } pk; pk.h = ru.h;
            *(uint4*)&sfeat[m][Cn + ch] = pk.u;     // rel-half of the row
        }
    }
    __syncthreads();   // single-wave: just orders LDS writes before reads

    // GEMM: out[8 nodes][128] = feat[8][256] @ Wt[256][128], MFMA f16.
    // This wave computes all 8 output tiles; acc rows >= 8 are garbage, unstored.
    floatx4 acc[8];
#pragma unroll
    for (int tl = 0; tl < 8; ++tl) acc[tl] = (floatx4){0.f, 0.f, 0.f, 0.f};
    const half8v* wh8 = (const half8v*)Wh;
#pragma unroll
    for (int step = 0; step < 8; ++step) {
        // A frag: A[m=lane&15][k = quad*8 + j], k-base = step*32
        half8v a = *(const half8v*)&sfeat[l16][step * 32 + q * 8];
#pragma unroll
        for (int tl = 0; tl < 8; ++tl) {
            half8v bf = wh8[(tl * 8 + step) * 64 + lane];
            acc[tl] = __builtin_amdgcn_mfma_f32_16x16x32_f16(a, bf, acc[tl], 0, 0, 0);
        }
    }
    // C/D layout: col = lane&15, row = q*4 + reg; valid rows 0..7 -> q < 2
    if (q < 2) {
#pragma unroll
        for (int tl = 0; tl < 8; ++tl) {
            const int o = tl * 16 + l16;
            const float bb = bias[o];
#pragma unroll
            for (int r2 = 0; r2 < 4; ++r2) {
                int g = gbase + q * 4 + r2;
                out[g * OUTn + o] = fmaxf(acc[tl][r2] + bb, 0.f);
            }
        }
    }
}

extern "C" void kernel_launch(void* const* d_in, const int* in_sizes, int n_in,
                              void* d_out, int out_size, void* d_ws, size_t ws_size,
                              hipStream_t stream) {
    const float* x = (const float*)d_in[0];
    const int* edge = (const int*)d_in[1];
    const float* W = (const float*)d_in[2];
    const float* bias = (const float*)d_in[3];
    float* out = (float*)d_out;

    _Float16* Wh = (_Float16*)d_ws;                        // 64 KB
    _Float16* xh = (_Float16*)((char*)d_ws + 65536);       // 10.24 MB

    prep<<<2516, 256, 0, stream>>>(x, W, xh, Wh);
    mrconv_kernel<<<5000, 64, 0, stream>>>(xh, edge, Wh, bias, out);
}